// Round 1
// baseline (276.051 us; speedup 1.0000x reference)
//
#include <hip/hip_runtime.h>
#include <math.h>

// Location-aware attention (ESPnet AttLoc), T=50000, ATT=EPROJ=512, DUNITS=1024,
// CH=10, K=201, FILTS=100, SCALING=2.
//
// K0: conv1d(att_prev) -> ws_aconv[T][10]; dec_z @ w_dec.T -> ws_dec[512]
// K1: e[t] = gvec . tanh(pre[t] + dec + aconv[t]@w_att^T) ; y = 2*(e+b+mask)
//     -> ws_e[T]; per-block online (max, sumexp) partials -> ws_ms
// K2: merge partials -> (M, 1/S); zero d_out[0:512]
// K3: w[t] = exp(y-M)/S -> d_out[512+t]; partial c = sum w[t]*enc_h[t] -> ws_c
// K4: reduce ws_c -> d_out[0:512] (atomicAdd, 32 per address)

constexpr int ATT    = 512;
constexpr int CH     = 10;
constexpr int KW     = 201;
constexpr int FILTS  = 100;
constexpr int DUNITS = 1024;
constexpr int NB1    = 1024;   // K1 grid
constexpr int NB3    = 256;    // K3 grid
constexpr float SCALING = 2.0f;

__device__ __forceinline__ float wave_reduce_sum(float v) {
    #pragma unroll
    for (int off = 32; off > 0; off >>= 1) v += __shfl_xor(v, off, 64);
    return v;
}

__device__ __forceinline__ float fast_tanh(float x) {
    // clamp keeps exp finite; tanh(15) == 1 to f32 precision
    x = fminf(fmaxf(x, -15.f), 15.f);
    float e = __expf(2.f * x);
    return __fdividef(e - 1.f, e + 1.f);
}

// ---------------- K0: conv over att_prev + dec projection ----------------
__global__ __launch_bounds__(256, 4) void k0_conv_dec(
    const float* __restrict__ att_prev,
    const float* __restrict__ conv_w,   // [CH][1][KW]
    const float* __restrict__ dec_z,    // [DUNITS]
    const float* __restrict__ w_dec,    // [ATT][DUNITS]
    float* __restrict__ ws_aconv,       // [T][CH]
    float* __restrict__ ws_dec,         // [ATT]
    int T, int nbconv)
{
    if ((int)blockIdx.x < nbconv) {
        __shared__ float s_ap[256 + KW - 1];   // 456
        __shared__ float s_w[CH * KW];         // 2010
        const int t0 = blockIdx.x * 256;
        for (int i = threadIdx.x; i < 256 + KW - 1; i += 256) {
            int t = t0 - FILTS + i;
            s_ap[i] = (t >= 0 && t < T) ? att_prev[t] : 0.f;
        }
        for (int i = threadIdx.x; i < CH * KW; i += 256) s_w[i] = conv_w[i];
        __syncthreads();
        const int t = t0 + threadIdx.x;
        if (t < T) {
            float acc[CH];
            #pragma unroll
            for (int c = 0; c < CH; ++c) acc[c] = 0.f;
            for (int k = 0; k < KW; ++k) {
                float x = s_ap[threadIdx.x + k];
                #pragma unroll
                for (int c = 0; c < CH; ++c) acc[c] += x * s_w[c * KW + k];
            }
            #pragma unroll
            for (int c = 0; c < CH; ++c) ws_aconv[t * CH + c] = acc[c];
        }
    } else {
        // dec projection: one wave per output dim a
        const int b    = blockIdx.x - nbconv;          // 0..127
        const int wid  = threadIdx.x >> 6;
        const int lane = threadIdx.x & 63;
        const int a    = b * 4 + wid;                  // 0..511
        const float4* wd = (const float4*)(w_dec + a * DUNITS);
        const float4* dz = (const float4*)dec_z;
        float acc = 0.f;
        #pragma unroll
        for (int q = 0; q < 4; ++q) {
            float4 wv = wd[lane + q * 64];
            float4 zv = dz[lane + q * 64];
            acc += wv.x * zv.x + wv.y * zv.y + wv.z * zv.z + wv.w * zv.w;
        }
        acc = wave_reduce_sum(acc);
        if (lane == 0) ws_dec[a] = acc;
    }
}

// ---------------- K1: scores ----------------
__global__ __launch_bounds__(256, 3) void k1_scores(
    const float* __restrict__ pre,       // [T][512]
    const float* __restrict__ mask,      // [T]
    const float* __restrict__ w_att,     // [512][10]
    const float* __restrict__ w_gvec,    // [512]
    const float* __restrict__ b_gvec,    // [1]
    const float* __restrict__ ws_dec,    // [512]
    const float* __restrict__ ws_aconv,  // [T][10]
    float* __restrict__ ws_e,            // [T]
    float* __restrict__ ws_ms,           // [NB1*2]
    int T)
{
    __shared__ float s_watt[ATT * CH];   // 20 KiB
    __shared__ float s_m[4], s_s[4];
    for (int i = threadIdx.x; i < ATT * CH; i += 256) s_watt[i] = w_att[i];
    __syncthreads();

    const int wid  = threadIdx.x >> 6;
    const int lane = threadIdx.x & 63;

    // lane owns a-dims: j<4 -> lane*4+j ; j>=4 -> 256+lane*4+(j-4)
    float wa[8][CH];
    #pragma unroll
    for (int j = 0; j < 4; ++j) {
        #pragma unroll
        for (int c = 0; c < CH; ++c) {
            wa[j][c]     = s_watt[(lane * 4 + j) * CH + c];
            wa[4 + j][c] = s_watt[(256 + lane * 4 + j) * CH + c];
        }
    }
    const float4 dlo = ((const float4*)ws_dec)[lane];
    const float4 dhi = ((const float4*)ws_dec)[64 + lane];
    const float4 glo = ((const float4*)w_gvec)[lane];
    const float4 ghi = ((const float4*)w_gvec)[64 + lane];
    const float  bg  = b_gvec[0];

    float m = -INFINITY, s = 0.f;
    const float4* pre4 = (const float4*)pre;
    const int gw = blockIdx.x * 4 + wid;

    for (int tb = gw * 4; tb < T; tb += NB1 * 4 * 4) {
        float4 p0[4], p1[4];
        #pragma unroll
        for (int i = 0; i < 4; ++i) {
            int t = tb + i;
            if (t < T) {
                p0[i] = pre4[t * 128 + lane];
                p1[i] = pre4[t * 128 + 64 + lane];
            }
        }
        #pragma unroll
        for (int i = 0; i < 4; ++i) {
            int t = tb + i;
            if (t >= T) break;
            float ac[CH];
            #pragma unroll
            for (int c = 0; c < CH; ++c) ac[c] = ws_aconv[t * CH + c];
            float av[8];
            #pragma unroll
            for (int j = 0; j < 8; ++j) {
                float v = 0.f;
                #pragma unroll
                for (int c = 0; c < CH; ++c) v += ac[c] * wa[j][c];
                av[j] = v;
            }
            float x0 = fast_tanh(p0[i].x + dlo.x + av[0]);
            float x1 = fast_tanh(p0[i].y + dlo.y + av[1]);
            float x2 = fast_tanh(p0[i].z + dlo.z + av[2]);
            float x3 = fast_tanh(p0[i].w + dlo.w + av[3]);
            float x4 = fast_tanh(p1[i].x + dhi.x + av[4]);
            float x5 = fast_tanh(p1[i].y + dhi.y + av[5]);
            float x6 = fast_tanh(p1[i].z + dhi.z + av[6]);
            float x7 = fast_tanh(p1[i].w + dhi.w + av[7]);
            float acc = glo.x * x0 + glo.y * x1 + glo.z * x2 + glo.w * x3
                      + ghi.x * x4 + ghi.y * x5 + ghi.z * x6 + ghi.w * x7;
            acc = wave_reduce_sum(acc);
            float y = SCALING * (acc + bg + mask[t]);
            if (lane == 0) ws_e[t] = y;
            // online (max, sumexp) — identical in all lanes
            float nm = fmaxf(m, y);
            s = s * __expf(m - nm) + __expf(y - nm);
            m = nm;
        }
    }
    if (lane == 0) { s_m[wid] = m; s_s[wid] = s; }
    __syncthreads();
    if (threadIdx.x == 0) {
        float M = s_m[0], S = s_s[0];
        #pragma unroll
        for (int w = 1; w < 4; ++w) {
            float m2 = s_m[w], s2 = s_s[w];
            float nm = fmaxf(M, m2);
            S = S * __expf(M - nm) + s2 * __expf(m2 - nm);
            M = nm;
        }
        ws_ms[blockIdx.x * 2]     = M;
        ws_ms[blockIdx.x * 2 + 1] = S;
    }
}

// ---------------- K2: merge softmax partials, zero c ----------------
__global__ __launch_bounds__(256, 4) void k2_merge(
    const float* __restrict__ ws_ms, float* __restrict__ ws_glob,
    float* __restrict__ out, int nb)
{
    __shared__ float s_m[256], s_s[256];
    float m = -INFINITY, s = 0.f;
    for (int i = threadIdx.x; i < nb; i += 256) {
        float m2 = ws_ms[i * 2], s2 = ws_ms[i * 2 + 1];
        float nm = fmaxf(m, m2);
        s = s * __expf(m - nm) + s2 * __expf(m2 - nm);
        m = nm;
    }
    s_m[threadIdx.x] = m; s_s[threadIdx.x] = s;
    __syncthreads();
    for (int off = 128; off > 0; off >>= 1) {
        if ((int)threadIdx.x < off) {
            float M = s_m[threadIdx.x], S = s_s[threadIdx.x];
            float m2 = s_m[threadIdx.x + off], s2 = s_s[threadIdx.x + off];
            float nm = fmaxf(M, m2);
            s_s[threadIdx.x] = S * __expf(M - nm) + s2 * __expf(m2 - nm);
            s_m[threadIdx.x] = nm;
        }
        __syncthreads();
    }
    if (threadIdx.x == 0) { ws_glob[0] = s_m[0]; ws_glob[1] = 1.f / s_s[0]; }
    // zero context output for K4's atomics
    out[threadIdx.x]       = 0.f;
    out[threadIdx.x + 256] = 0.f;
}

// ---------------- K3: weights + partial context ----------------
__global__ __launch_bounds__(256, 4) void k3_ctx(
    const float* __restrict__ enc_h,     // [T][512]
    const float* __restrict__ ws_e,      // [T]
    const float* __restrict__ ws_glob,   // M, 1/S
    float* __restrict__ out,             // d_out: [0:512)=c, [512:512+T)=w
    float* __restrict__ ws_c,            // [NB3][512]
    int T)
{
    const int wid  = threadIdx.x >> 6;
    const int lane = threadIdx.x & 63;
    const float M  = ws_glob[0];
    const float IS = ws_glob[1];
    const float4* eh4 = (const float4*)enc_h;

    float4 a0 = make_float4(0.f, 0.f, 0.f, 0.f);
    float4 a1 = make_float4(0.f, 0.f, 0.f, 0.f);
    const int gw = blockIdx.x * 4 + wid;

    for (int tb = gw * 8; tb < T; tb += NB3 * 4 * 8) {
        float4 e0[8], e1[8];
        float  y[8];
        #pragma unroll
        for (int i = 0; i < 8; ++i) {
            int t = tb + i;
            if (t < T) {
                e0[i] = eh4[t * 128 + lane];
                e1[i] = eh4[t * 128 + 64 + lane];
                y[i]  = ws_e[t];
            }
        }
        #pragma unroll
        for (int i = 0; i < 8; ++i) {
            int t = tb + i;
            if (t >= T) break;
            float w = __expf(y[i] - M) * IS;
            if (lane == 0) out[ATT + t] = w;
            a0.x += w * e0[i].x; a0.y += w * e0[i].y;
            a0.z += w * e0[i].z; a0.w += w * e0[i].w;
            a1.x += w * e1[i].x; a1.y += w * e1[i].y;
            a1.z += w * e1[i].z; a1.w += w * e1[i].w;
        }
    }

    __shared__ float4 s_c[4 * 128];   // 8 KiB = [wave][512 floats]
    s_c[wid * 128 + lane]      = a0;
    s_c[wid * 128 + 64 + lane] = a1;
    __syncthreads();
    const float* sc = (const float*)s_c;
    for (int a = threadIdx.x; a < ATT; a += 256) {
        float v = sc[a] + sc[512 + a] + sc[1024 + a] + sc[1536 + a];
        ws_c[blockIdx.x * ATT + a] = v;
    }
}

// ---------------- K4: reduce partial contexts ----------------
__global__ __launch_bounds__(256, 4) void k4_reduce(
    const float* __restrict__ ws_c, float* __restrict__ out)
{
    const int gt  = blockIdx.x * 256 + threadIdx.x;  // 0..16383
    const int a   = gt & (ATT - 1);
    const int grp = gt >> 9;                         // 0..31
    float v = 0.f;
    #pragma unroll
    for (int i = 0; i < 8; ++i) v += ws_c[(grp * 8 + i) * ATT + a];
    atomicAdd(&out[a], v);
}

extern "C" void kernel_launch(void* const* d_in, const int* in_sizes, int n_in,
                              void* d_out, int out_size, void* d_ws, size_t ws_size,
                              hipStream_t stream)
{
    const float* dec_z    = (const float*)d_in[0];
    const float* att_prev = (const float*)d_in[1];
    const float* pre      = (const float*)d_in[2];
    const float* enc_h    = (const float*)d_in[3];
    const float* mask     = (const float*)d_in[4];
    const float* conv_w   = (const float*)d_in[5];
    const float* w_att    = (const float*)d_in[6];
    const float* w_dec    = (const float*)d_in[7];
    const float* w_gvec   = (const float*)d_in[8];
    const float* b_gvec   = (const float*)d_in[9];
    const int T = in_sizes[1];

    float* ws       = (float*)d_ws;
    float* ws_dec   = ws;                    // 512
    float* ws_aconv = ws_dec + ATT;          // T*CH
    float* ws_e     = ws_aconv + (size_t)T * CH;  // T
    float* ws_ms    = ws_e + T;              // NB1*2
    float* ws_glob  = ws_ms + NB1 * 2;       // 2 (+pad to 4)
    float* ws_c     = ws_glob + 4;           // NB3*512
    float* out      = (float*)d_out;

    const int nbconv = (T + 255) / 256;

    hipLaunchKernelGGL(k0_conv_dec, dim3(nbconv + ATT / 4), dim3(256), 0, stream,
                       att_prev, conv_w, dec_z, w_dec, ws_aconv, ws_dec, T, nbconv);
    hipLaunchKernelGGL(k1_scores, dim3(NB1), dim3(256), 0, stream,
                       pre, mask, w_att, w_gvec, b_gvec, ws_dec, ws_aconv,
                       ws_e, ws_ms, T);
    hipLaunchKernelGGL(k2_merge, dim3(1), dim3(256), 0, stream,
                       ws_ms, ws_glob, out, NB1);
    hipLaunchKernelGGL(k3_ctx, dim3(NB3), dim3(256), 0, stream,
                       enc_h, ws_e, ws_glob, out, ws_c, T);
    hipLaunchKernelGGL(k4_reduce, dim3(64), dim3(256), 0, stream,
                       ws_c, out);
}

// Round 4
// 273.479 us; speedup vs baseline: 1.0094x; 1.0094x over previous
//
#include <hip/hip_runtime.h>
#include <math.h>

// Location-aware attention (ESPnet AttLoc), T=50000, ATT=EPROJ=512, DUNITS=1024,
// CH=10, K=201, FILTS=100, SCALING=2.
//
// K0: conv1d(att_prev) -> ws_aconv[T][12] (stride-12 padded for float4 reads);
//     dec_z @ w_dec.T -> ws_dec[512]; zero d_out[0:512] for K3's atomics.
// K1: e[t] = gvec . tanh(pre[t] + dec + aconv[t]@w_att^T); y = 2*(e+b+mask)
//     -> ws_e[T]; per-block online (max, sumexp) partials -> ws_ms.
// K3: per-block merge of ws_ms -> (M, 1/S); w[t]=exp(y-M)/S -> d_out[512+t];
//     context accumulated per block then atomicAdd into d_out[0:512].

constexpr int ATT    = 512;
constexpr int CH     = 10;
constexpr int PCH    = 12;     // padded channel stride (48 B -> float4-aligned)
constexpr int KW     = 201;
constexpr int FILTS  = 100;
constexpr int DUNITS = 1024;
constexpr int NB1    = 1024;   // K1 grid
constexpr int NB3    = 1024;   // K3 grid
constexpr int CT     = 64;     // t-tile per conv block
constexpr float SCALING = 2.0f;

__device__ __forceinline__ float wave_reduce_sum(float v) {
    #pragma unroll
    for (int off = 32; off > 0; off >>= 1) v += __shfl_xor(v, off, 64);
    return v;
}

__device__ __forceinline__ float fast_tanh(float x) {
    x = fminf(fmaxf(x, -15.f), 15.f);
    float e = __expf(2.f * x);
    return __fdividef(e - 1.f, e + 1.f);
}

// ---------------- K0: conv over att_prev + dec projection + zero c ----------------
__global__ __launch_bounds__(256, 4) void k0_conv_dec(
    const float* __restrict__ att_prev,
    const float* __restrict__ conv_w,   // [CH][1][KW]
    const float* __restrict__ dec_z,    // [DUNITS]
    const float* __restrict__ w_dec,    // [ATT][DUNITS]
    float* __restrict__ ws_aconv,       // [T][PCH]
    float* __restrict__ ws_dec,         // [ATT]
    float* __restrict__ out,            // d_out (zero [0:512))
    int T, int nbconv)
{
    if ((int)blockIdx.x < nbconv) {
        __shared__ float s_ap[CT + KW - 1];     // 264
        __shared__ float s_wt[KW * 12];         // transposed weights [k][c], pad 12
        __shared__ float s_part[4 * CT * CH];   // per-kq partials: 2560 floats
        const int t0 = blockIdx.x * CT;
        for (int i = threadIdx.x; i < CT + KW - 1; i += 256) {
            int t = t0 - FILTS + i;
            s_ap[i] = (t >= 0 && t < T) ? att_prev[t] : 0.f;
        }
        for (int i = threadIdx.x; i < CH * KW; i += 256) {
            int c = i % CH, k = i / CH;
            s_wt[k * 12 + c] = conv_w[c * KW + k];
        }
        __syncthreads();
        const int tl = threadIdx.x & 63;   // t within tile
        const int kq = threadIdx.x >> 6;   // tap quarter (wave id)
        float acc[CH];
        #pragma unroll
        for (int c = 0; c < CH; ++c) acc[c] = 0.f;
        // taps k ≡ kq (mod 4); all lanes of a wave share k -> LDS broadcast reads
        for (int k = kq; k < KW; k += 4) {
            float x = s_ap[tl + k];
            const float4 w0 = *(const float4*)&s_wt[k * 12];
            const float4 w1 = *(const float4*)&s_wt[k * 12 + 4];
            const float2 w2 = *(const float2*)&s_wt[k * 12 + 8];
            acc[0] += x * w0.x; acc[1] += x * w0.y;
            acc[2] += x * w0.z; acc[3] += x * w0.w;
            acc[4] += x * w1.x; acc[5] += x * w1.y;
            acc[6] += x * w1.z; acc[7] += x * w1.w;
            acc[8] += x * w2.x; acc[9] += x * w2.y;
        }
        #pragma unroll
        for (int c = 0; c < CH; ++c) s_part[kq * (CT * CH) + tl * CH + c] = acc[c];
        __syncthreads();
        // write stride-PCH padded output (pad lanes get 0)
        for (int idx = threadIdx.x; idx < CT * PCH; idx += 256) {
            int t = idx / PCH, c = idx % PCH;
            float v = 0.f;
            if (c < CH) {
                int j = t * CH + c;
                v = s_part[j] + s_part[CT * CH + j]
                  + s_part[2 * CT * CH + j] + s_part[3 * CT * CH + j];
            }
            if (t0 + t < T) ws_aconv[(size_t)(t0 + t) * PCH + c] = v;
        }
    } else {
        // dec projection: one wave per output dim a; also zero context output
        const int b    = blockIdx.x - nbconv;          // 0..127
        const int wid  = threadIdx.x >> 6;
        const int lane = threadIdx.x & 63;
        const int a    = b * 4 + wid;                  // 0..511
        if (threadIdx.x < 4) out[b * 4 + threadIdx.x] = 0.f;
        const float4* wd = (const float4*)(w_dec + (size_t)a * DUNITS);
        const float4* dz = (const float4*)dec_z;
        float acc = 0.f;
        #pragma unroll
        for (int q = 0; q < 4; ++q) {
            float4 wv = wd[lane + q * 64];
            float4 zv = dz[lane + q * 64];
            acc += wv.x * zv.x + wv.y * zv.y + wv.z * zv.z + wv.w * zv.w;
        }
        acc = wave_reduce_sum(acc);
        if (lane == 0) ws_dec[a] = acc;
    }
}

// ---------------- K1: scores ----------------
__global__ __launch_bounds__(256, 3) void k1_scores(
    const float* __restrict__ pre,       // [T][512]
    const float* __restrict__ mask,      // [T]
    const float* __restrict__ w_att,     // [512][10]
    const float* __restrict__ w_gvec,    // [512]
    const float* __restrict__ b_gvec,    // [1]
    const float* __restrict__ ws_dec,    // [512]
    const float* __restrict__ ws_aconv,  // [T][PCH]
    float* __restrict__ ws_e,            // [T]
    float* __restrict__ ws_ms,           // [NB1*2]
    int T)
{
    __shared__ float s_watt[ATT * CH];   // 20 KiB
    __shared__ float s_m[4], s_s[4];
    for (int i = threadIdx.x; i < ATT * CH; i += 256) s_watt[i] = w_att[i];
    __syncthreads();

    const int wid  = threadIdx.x >> 6;
    const int lane = threadIdx.x & 63;

    // lane owns a-dims: j<4 -> lane*4+j ; j>=4 -> 256+lane*4+(j-4)
    float wa[8][CH];
    #pragma unroll
    for (int j = 0; j < 4; ++j) {
        #pragma unroll
        for (int c = 0; c < CH; ++c) {
            wa[j][c]     = s_watt[(lane * 4 + j) * CH + c];
            wa[4 + j][c] = s_watt[(256 + lane * 4 + j) * CH + c];
        }
    }
    const float4 dlo = ((const float4*)ws_dec)[lane];
    const float4 dhi = ((const float4*)ws_dec)[64 + lane];
    const float4 glo = ((const float4*)w_gvec)[lane];
    const float4 ghi = ((const float4*)w_gvec)[64 + lane];
    const float  bg  = b_gvec[0];

    float m = -INFINITY, s = 0.f;
    const float4* pre4 = (const float4*)pre;
    const float4* ac4  = (const float4*)ws_aconv;   // stride PCH/4 = 3 per t
    const int gw = blockIdx.x * 4 + wid;

    for (int tb = gw * 4; tb < T; tb += NB1 * 4 * 4) {
        float4 p0[4], p1[4];
        float  msk[4];
        #pragma unroll
        for (int i = 0; i < 4; ++i) {
            int t = tb + i;
            if (t < T) {
                p0[i]  = pre4[(size_t)t * 128 + lane];
                p1[i]  = pre4[(size_t)t * 128 + 64 + lane];
                msk[i] = mask[t];
            }
        }
        #pragma unroll
        for (int i = 0; i < 4; ++i) {
            int t = tb + i;
            if (t >= T) break;
            float ac[12];
            *(float4*)&ac[0] = ac4[(size_t)t * 3 + 0];
            *(float4*)&ac[4] = ac4[(size_t)t * 3 + 1];
            *(float4*)&ac[8] = ac4[(size_t)t * 3 + 2];
            float av[8];
            #pragma unroll
            for (int j = 0; j < 8; ++j) {
                float v = 0.f;
                #pragma unroll
                for (int c = 0; c < CH; ++c) v += ac[c] * wa[j][c];
                av[j] = v;
            }
            float x0 = fast_tanh(p0[i].x + dlo.x + av[0]);
            float x1 = fast_tanh(p0[i].y + dlo.y + av[1]);
            float x2 = fast_tanh(p0[i].z + dlo.z + av[2]);
            float x3 = fast_tanh(p0[i].w + dlo.w + av[3]);
            float x4 = fast_tanh(p1[i].x + dhi.x + av[4]);
            float x5 = fast_tanh(p1[i].y + dhi.y + av[5]);
            float x6 = fast_tanh(p1[i].z + dhi.z + av[6]);
            float x7 = fast_tanh(p1[i].w + dhi.w + av[7]);
            float acc = glo.x * x0 + glo.y * x1 + glo.z * x2 + glo.w * x3
                      + ghi.x * x4 + ghi.y * x5 + ghi.z * x6 + ghi.w * x7;
            acc = wave_reduce_sum(acc);
            float y = SCALING * (acc + bg + msk[i]);
            if (lane == 0) ws_e[t] = y;
            float nm = fmaxf(m, y);
            s = s * __expf(m - nm) + __expf(y - nm);
            m = nm;
        }
    }
    if (lane == 0) { s_m[wid] = m; s_s[wid] = s; }
    __syncthreads();
    if (threadIdx.x == 0) {
        float M = s_m[0], S = s_s[0];
        #pragma unroll
        for (int w = 1; w < 4; ++w) {
            float m2 = s_m[w], s2 = s_s[w];
            float nm = fmaxf(M, m2);
            S = S * __expf(M - nm) + s2 * __expf(m2 - nm);
            M = nm;
        }
        ws_ms[blockIdx.x * 2]     = M;
        ws_ms[blockIdx.x * 2 + 1] = S;
    }
}

// ---------------- K3: merge partials + weights + context ----------------
__global__ __launch_bounds__(256, 4) void k3_ctx(
    const float* __restrict__ enc_h,     // [T][512]
    const float* __restrict__ ws_e,      // [T]
    const float* __restrict__ ws_ms,     // [NB1*2]
    float* __restrict__ out,             // d_out: [0:512)=c (pre-zeroed), [512:512+T)=w
    int T)
{
    // --- per-block redundant merge of softmax partials ---
    __shared__ float s_m[256], s_s[256];
    {
        float m = -INFINITY, s = 0.f;
        for (int i = threadIdx.x; i < NB1; i += 256) {
            float m2 = ws_ms[i * 2], s2 = ws_ms[i * 2 + 1];
            float nm = fmaxf(m, m2);
            s = s * __expf(m - nm) + s2 * __expf(m2 - nm);
            m = nm;
        }
        s_m[threadIdx.x] = m; s_s[threadIdx.x] = s;
        __syncthreads();
        for (int off = 128; off > 0; off >>= 1) {
            if ((int)threadIdx.x < off) {
                float M = s_m[threadIdx.x], S = s_s[threadIdx.x];
                float m2 = s_m[threadIdx.x + off], s2 = s_s[threadIdx.x + off];
                float nm = fmaxf(M, m2);
                s_s[threadIdx.x] = S * __expf(M - nm) + s2 * __expf(m2 - nm);
                s_m[threadIdx.x] = nm;
            }
            __syncthreads();
        }
    }
    const float M  = s_m[0];
    const float IS = 1.f / s_s[0];

    const int wid  = threadIdx.x >> 6;
    const int lane = threadIdx.x & 63;
    const float4* eh4 = (const float4*)enc_h;

    float4 a0 = make_float4(0.f, 0.f, 0.f, 0.f);
    float4 a1 = make_float4(0.f, 0.f, 0.f, 0.f);
    const int gw = blockIdx.x * 4 + wid;

    for (int tb = gw * 4; tb < T; tb += NB3 * 4 * 4) {
        float4 e0[4], e1[4];
        float  y[4];
        #pragma unroll
        for (int i = 0; i < 4; ++i) {
            int t = tb + i;
            if (t < T) {
                e0[i] = eh4[(size_t)t * 128 + lane];
                e1[i] = eh4[(size_t)t * 128 + 64 + lane];
                y[i]  = ws_e[t];
            }
        }
        #pragma unroll
        for (int i = 0; i < 4; ++i) {
            int t = tb + i;
            if (t >= T) break;
            float w = __expf(y[i] - M) * IS;
            if (lane == 0) out[ATT + t] = w;
            a0.x += w * e0[i].x; a0.y += w * e0[i].y;
            a0.z += w * e0[i].z; a0.w += w * e0[i].w;
            a1.x += w * e1[i].x; a1.y += w * e1[i].y;
            a1.z += w * e1[i].z; a1.w += w * e1[i].w;
        }
    }

    __shared__ float4 s_c[4 * 128];   // 8 KiB = [wave][512 floats]
    s_c[wid * 128 + lane]      = a0;
    s_c[wid * 128 + 64 + lane] = a1;
    __syncthreads();
    const float* sc = (const float*)s_c;
    for (int a = threadIdx.x; a < ATT; a += 256) {
        float v = sc[a] + sc[512 + a] + sc[1024 + a] + sc[1536 + a];
        atomicAdd(&out[a], v);
    }
}

extern "C" void kernel_launch(void* const* d_in, const int* in_sizes, int n_in,
                              void* d_out, int out_size, void* d_ws, size_t ws_size,
                              hipStream_t stream)
{
    const float* dec_z    = (const float*)d_in[0];
    const float* att_prev = (const float*)d_in[1];
    const float* pre      = (const float*)d_in[2];
    const float* enc_h    = (const float*)d_in[3];
    const float* mask     = (const float*)d_in[4];
    const float* conv_w   = (const float*)d_in[5];
    const float* w_att    = (const float*)d_in[6];
    const float* w_dec    = (const float*)d_in[7];
    const float* w_gvec   = (const float*)d_in[8];
    const float* b_gvec   = (const float*)d_in[9];
    const int T = in_sizes[1];

    float* ws       = (float*)d_ws;
    float* ws_dec   = ws;                          // 512
    float* ws_aconv = ws_dec + ATT;                // T*PCH
    float* ws_e     = ws_aconv + (size_t)T * PCH;  // T
    float* ws_ms    = ws_e + T;                    // NB1*2
    float* out      = (float*)d_out;

    const int nbconv = (T + CT - 1) / CT;

    hipLaunchKernelGGL(k0_conv_dec, dim3(nbconv + ATT / 4), dim3(256), 0, stream,
                       att_prev, conv_w, dec_z, w_dec, ws_aconv, ws_dec, out, T, nbconv);
    hipLaunchKernelGGL(k1_scores, dim3(NB1), dim3(256), 0, stream,
                       pre, mask, w_att, w_gvec, b_gvec, ws_dec, ws_aconv,
                       ws_e, ws_ms, T);
    hipLaunchKernelGGL(k3_ctx, dim3(NB3), dim3(256), 0, stream,
                       enc_h, ws_e, ws_ms, out, T);
}